// Round 11
// baseline (430.606 us; speedup 1.0000x reference)
//
#include <hip/hip_runtime.h>
#include <hip/hip_cooperative_groups.h>

namespace cg = cooperative_groups;

#define OUTC 512
#define INC 512
#define NTILE 4
#define TCOL 128   // OUTC / NTILE
#define LDA 72     // 64 + 8 ushort pad: conflict-free ds_read_b128
#define TPB 256
#define GMAX 768
#define SHBYTES 27648

typedef __bf16 bf16x8 __attribute__((ext_vector_type(8)));
typedef float f32x4 __attribute__((ext_vector_type(4)));

static __device__ __forceinline__ unsigned short f2bf(float f) {
    unsigned u = __float_as_uint(f);
    unsigned r = u + 0x7fffu + ((u >> 16) & 1u);  // RNE
    return (unsigned short)(r >> 16);
}
static __device__ __forceinline__ float bflo(unsigned r) { return __uint_as_float(r << 16); }
static __device__ __forceinline__ float bfhi(unsigned r) { return __uint_as_float(r & 0xffff0000u); }
static __device__ __forceinline__ void acc8s(float* a, uint4 v, float n) {
    a[0] += n * bflo(v.x); a[1] += n * bfhi(v.x);
    a[2] += n * bflo(v.y); a[3] += n * bfhi(v.y);
    a[4] += n * bflo(v.z); a[5] += n * bfhi(v.z);
    a[6] += n * bflo(v.w); a[7] += n * bfhi(v.w);
}

// ============ P0: X->bf16 | degree count | W->bf16^T | temb ============
static __device__ __forceinline__ void phase0(
        const float* __restrict__ x, const float* __restrict__ W,
        const float* __restrict__ t_emb, const float* __restrict__ Wt,
        const float* __restrict__ bt, const float* __restrict__ bias,
        const int* __restrict__ dst, int* __restrict__ counts,
        unsigned short* __restrict__ xb, unsigned short* __restrict__ wtb,
        float* __restrict__ temb, int N, int E, int TC, int Mpad, char* shraw) {
    const int G = gridDim.x, bid = blockIdx.x, tid = threadIdx.x;
    const int gtid = bid * TPB + tid;
    const int NTH = G * TPB;

    // X -> bf16, zero-padded rows to Mpad (8 elems per thread-iter)
    for (int idx = gtid; idx < Mpad * (INC / 8); idx += NTH) {
        int row = idx >> 6;
        int kg = (idx & 63) * 8;
        ushort4 h0 = make_ushort4(0, 0, 0, 0), h1 = make_ushort4(0, 0, 0, 0);
        if (row < N) {
            float4 v0 = *(const float4*)(x + (size_t)row * INC + kg);
            float4 v1 = *(const float4*)(x + (size_t)row * INC + kg + 4);
            h0 = make_ushort4(f2bf(v0.x), f2bf(v0.y), f2bf(v0.z), f2bf(v0.w));
            h1 = make_ushort4(f2bf(v1.x), f2bf(v1.y), f2bf(v1.z), f2bf(v1.w));
        }
        *(ushort4*)(xb + (size_t)row * INC + kg) = h0;
        *(ushort4*)(xb + (size_t)row * INC + kg + 4) = h1;
    }
    // in-degree histogram
    for (int e = gtid; e < E; e += NTH)
        atomicAdd(&counts[dst[e]], 1);
    // W[k][n] -> wtb[n][k], 32x32 LDS tiles, block-stride
    float* sm = (float*)shraw;
    for (int b2 = bid; b2 < 256; b2 += G) {
        int bk = (b2 & 15) * 32, bn = (b2 >> 4) * 32;
        int tx = tid & 31, ty = tid >> 5;  // ty 0..7
        __syncthreads();
        for (int r = ty; r < 32; r += 8)
            sm[r * 33 + tx] = W[(size_t)(bk + r) * OUTC + bn + tx];
        __syncthreads();
        for (int r = ty; r < 32; r += 8)
            wtb[(size_t)(bn + r) * INC + bk + tx] = f2bf(sm[tx * 33 + r]);
    }
    // temb: one thread per output column (coalesced across j)
    for (int j = gtid; j < OUTC; j += NTH) {
        float s = 0.0f;
        for (int k = 0; k < TC; ++k) s += t_emb[k] * Wt[(size_t)k * OUTC + j];
        temb[j] = s + bt[j] + bias[j];
    }
}

// ============ P1a: bump-alloc CSR offsets (wave prefix + 1 atomic) ============
static __device__ __forceinline__ void phase1_alloc(
        const int* __restrict__ counts, int* __restrict__ row_start,
        int* __restrict__ cursor, float* __restrict__ dinv,
        int* __restrict__ allocCtr, int N) {
    const int lane = threadIdx.x & 63;
    const int gwave = (blockIdx.x * TPB + threadIdx.x) >> 6;
    const int nwaves = gridDim.x * (TPB / 64);
    for (int c0 = gwave * 64; c0 < N; c0 += nwaves * 64) {
        int d = c0 + lane;
        int deg = (d < N) ? counts[d] : 0;
        int incl = deg;
#pragma unroll
        for (int off = 1; off < 64; off <<= 1) {
            int v = __shfl_up(incl, off, 64);
            if (lane >= off) incl += v;
        }
        int wtot = __shfl(incl, 63, 64);
        int base = 0;
        if (lane == 63) base = atomicAdd(allocCtr, wtot);
        base = __shfl(base, 63, 64);
        if (d < N) {
            int rs = base + incl - deg;
            row_start[d] = rs;
            cursor[d] = rs;
            dinv[d] = rsqrtf((float)deg + 1.0f);
        }
    }
}

// ============ P1b: LDS-staged MFMA GEMM, 128x64 tiles, block-stride ============
static __device__ __forceinline__ void phase1_gemm(
        const unsigned short* __restrict__ xb, const unsigned short* __restrict__ wtb,
        unsigned short* __restrict__ xwb, int Mpad, char* shraw) {
    unsigned short* la = (unsigned short*)shraw;                    // 128*LDA
    unsigned short* lb = (unsigned short*)(shraw + 128 * LDA * 2);  // 64*LDA
    const int G = gridDim.x, tid = threadIdx.x;
    const int GB = (Mpad / 128) * 8;
    const int lane = tid & 63;
    const int wave = tid >> 6;
    const int wm = wave * 32;
    const int l15 = lane & 15;
    const int k8 = (lane >> 4) * 8;
    const int rbase = (lane >> 4) * 4;

    for (int gb = blockIdx.x; gb < GB; gb += G) {
        const int n0 = (gb & 7) * 64;
        const int m0 = (gb >> 3) * 128;

        f32x4 acc[2][4];
#pragma unroll
        for (int t = 0; t < 2; ++t)
#pragma unroll
            for (int u = 0; u < 4; ++u)
                acc[t][u] = (f32x4){0.f, 0.f, 0.f, 0.f};

        __syncthreads();  // protect LDS reuse across gb iterations
        for (int k0 = 0; k0 < INC; k0 += 64) {
#pragma unroll
            for (int i = 0; i < 4; ++i) {
                int f = i * 256 + tid;
                int row = f >> 3, c = f & 7;
                uint4 v = *(const uint4*)(xb + (size_t)(m0 + row) * INC + k0 + c * 8);
                *(uint4*)(&la[row * LDA + c * 8]) = v;
            }
#pragma unroll
            for (int i = 0; i < 2; ++i) {
                int f = i * 256 + tid;
                int row = f >> 3, c = f & 7;
                uint4 v = *(const uint4*)(wtb + (size_t)(n0 + row) * INC + k0 + c * 8);
                *(uint4*)(&lb[row * LDA + c * 8]) = v;
            }
            __syncthreads();
#pragma unroll
            for (int kc = 0; kc < 64; kc += 32) {
                bf16x8 af0 = *(const bf16x8*)(&la[(wm + l15) * LDA + kc + k8]);
                bf16x8 af1 = *(const bf16x8*)(&la[(wm + 16 + l15) * LDA + kc + k8]);
#pragma unroll
                for (int u = 0; u < 4; ++u) {
                    bf16x8 bfr = *(const bf16x8*)(&lb[(u * 16 + l15) * LDA + kc + k8]);
                    acc[0][u] = __builtin_amdgcn_mfma_f32_16x16x32_bf16(af0, bfr, acc[0][u], 0, 0, 0);
                    acc[1][u] = __builtin_amdgcn_mfma_f32_16x16x32_bf16(af1, bfr, acc[1][u], 0, 0, 0);
                }
            }
            __syncthreads();
        }
#pragma unroll
        for (int t = 0; t < 2; ++t)
#pragma unroll
            for (int u = 0; u < 4; ++u) {
                int gcol = n0 + u * 16 + l15;
                unsigned short* p = xwb + (size_t)(gcol >> 7) * Mpad * TCOL + (gcol & 127);
#pragma unroll
                for (int r = 0; r < 4; ++r) {
                    int grow = m0 + wm + t * 16 + rbase + r;  // < Mpad
                    p[(size_t)grow * TCOL] = f2bf(acc[t][u][r]);
                }
            }
    }
}

// ============ P2: CSR scatter ============
static __device__ __forceinline__ void phase2(
        const int* __restrict__ src, const int* __restrict__ dst,
        int* __restrict__ cursor, int* __restrict__ esrc, int E) {
    const int gtid = blockIdx.x * TPB + threadIdx.x;
    const int NTH = gridDim.x * TPB;
    for (int e = gtid; e < E; e += NTH) {
        int d = dst[e];
        int pos = atomicAdd(&cursor[d], 1);
        esrc[pos] = src[e];
    }
}

// ============ P3: XCD-pinned column-tiled gather + epilogue ============
static __device__ __forceinline__ void phase3(
        const int* __restrict__ esrc, const int* __restrict__ row_start,
        const int* __restrict__ counts, const unsigned short* __restrict__ xwb,
        const float* __restrict__ dinv, const float* __restrict__ temb,
        float* __restrict__ out, int N, int Mpad) {
    const int G = gridDim.x, bid = blockIdx.x, tid = threadIdx.x;
    const int tile = (bid & 7) >> 1;   // XCD pair {2t,2t+1} -> tile t
    const int wid = tid >> 6;
    const int lane = tid & 63;
    const int slot = lane >> 4;        // 4 edges per row-load instruction
    const int c8 = (lane & 15) * 8;
    const unsigned short* basep = xwb + (size_t)tile * Mpad * TCOL + c8;
    const int ng = (bid >> 3) * 8 + (bid & 1) * 4 + wid;  // [0, G) per tile

    for (int node = ng; node < N; node += G) {
        const int s0 = row_start[node];
        const int s1 = s0 + counts[node];
        float a[8] = {0.f, 0.f, 0.f, 0.f, 0.f, 0.f, 0.f, 0.f};
        int i = s0;
        for (; i + 8 <= s1; i += 8) {
            int sA = esrc[i + slot];
            int sB = esrc[i + 4 + slot];
            float nA = dinv[sA];
            float nB = dinv[sB];
            uint4 vA = *(const uint4*)(basep + (size_t)sA * TCOL);
            uint4 vB = *(const uint4*)(basep + (size_t)sB * TCOL);
            acc8s(a, vA, nA);
            acc8s(a, vB, nB);
        }
        for (; i < s1; i += 4) {
            int idx = i + slot;
            int sA = (idx < s1) ? esrc[idx] : node;
            float nA = (idx < s1) ? dinv[sA] : 0.f;
            uint4 v = *(const uint4*)(basep + (size_t)sA * TCOL);
            acc8s(a, v, nA);
        }
#pragma unroll
        for (int k = 0; k < 8; ++k) {
            a[k] += __shfl_xor(a[k], 16, 64);
            a[k] += __shfl_xor(a[k], 32, 64);
        }
        const float di = dinv[node];
        {
            uint4 v = *(const uint4*)(basep + (size_t)node * TCOL);
            acc8s(a, v, di);  // self-loop term
        }
        if (slot < 2) {
            const int gc = tile * TCOL + c8 + slot * 4;
            float4 tv = *(const float4*)(temb + gc);
            float4 o;
            o.x = di * a[slot * 4 + 0] + tv.x;
            o.y = di * a[slot * 4 + 1] + tv.y;
            o.z = di * a[slot * 4 + 2] + tv.z;
            o.w = di * a[slot * 4 + 3] + tv.w;
            *(float4*)(out + (size_t)node * OUTC + gc) = o;
        }
    }
}

#define FULL_PARAMS \
        const float* __restrict__ x, const float* __restrict__ t_emb, \
        const int* __restrict__ src, const int* __restrict__ dst, \
        const float* __restrict__ W, const float* __restrict__ bias, \
        const float* __restrict__ Wt, const float* __restrict__ bt, \
        float* __restrict__ out, \
        unsigned short* __restrict__ xb, unsigned short* __restrict__ wtb, \
        unsigned short* __restrict__ xwb, \
        int* __restrict__ counts, int* __restrict__ row_start, \
        int* __restrict__ cursor, int* __restrict__ allocCtr, \
        float* __restrict__ dinv, int* __restrict__ esrc, \
        float* __restrict__ temb, \
        int N, int E, int TC, int Mpad

// ---- cooperative all-in-one ----
__global__ __launch_bounds__(TPB, 3) void k_all(FULL_PARAMS) {
    __shared__ __align__(16) char shraw[SHBYTES];
    cg::grid_group grid = cg::this_grid();
    phase0(x, W, t_emb, Wt, bt, bias, dst, counts, xb, wtb, temb, N, E, TC, Mpad, shraw);
    grid.sync();
    phase1_alloc(counts, row_start, cursor, dinv, allocCtr, N);
    phase1_gemm(xb, wtb, xwb, Mpad, shraw);
    grid.sync();
    phase2(src, dst, cursor, esrc, E);
    grid.sync();
    phase3(esrc, row_start, counts, xwb, dinv, temb, out, N, Mpad);
}

// ---- fallback: identical phases as 4 ordinary kernels ----
__global__ __launch_bounds__(TPB) void k_f0(FULL_PARAMS) {
    __shared__ __align__(16) char shraw[SHBYTES];
    phase0(x, W, t_emb, Wt, bt, bias, dst, counts, xb, wtb, temb, N, E, TC, Mpad, shraw);
}
__global__ __launch_bounds__(TPB) void k_f1(FULL_PARAMS) {
    __shared__ __align__(16) char shraw[SHBYTES];
    phase1_alloc(counts, row_start, cursor, dinv, allocCtr, N);
    phase1_gemm(xb, wtb, xwb, Mpad, shraw);
}
__global__ __launch_bounds__(TPB) void k_f2(FULL_PARAMS) {
    phase2(src, dst, cursor, esrc, E);
}
__global__ __launch_bounds__(TPB) void k_f3(FULL_PARAMS) {
    phase3(esrc, row_start, counts, xwb, dinv, temb, out, N, Mpad);
}

extern "C" void kernel_launch(void* const* d_in, const int* in_sizes, int n_in,
                              void* d_out, int out_size, void* d_ws, size_t ws_size,
                              hipStream_t stream) {
    const float* x     = (const float*)d_in[0];
    const float* t_emb = (const float*)d_in[1];
    const int*   ei    = (const int*)d_in[2];
    const float* W     = (const float*)d_in[3];
    const float* b     = (const float*)d_in[4];
    const float* Wt    = (const float*)d_in[5];
    const float* bt    = (const float*)d_in[6];
    float* out = (float*)d_out;

    int N  = in_sizes[0] / INC;    // 10000
    int E  = in_sizes[2] / 2;      // 160000
    int TC = in_sizes[1];          // 256
    int Mpad = (N + 127) & ~127;   // 10112

    char* ws = (char*)d_ws;
    size_t off = 0;
    unsigned short* xb  = (unsigned short*)(ws + off); off += (size_t)Mpad * INC * 2;
    unsigned short* xwb = (unsigned short*)(ws + off); off += (size_t)Mpad * OUTC * 2;
    unsigned short* wtb = (unsigned short*)(ws + off); off += (size_t)INC * OUTC * 2;
    float* dinv = (float*)(ws + off);      off += ((size_t)N * 4 + 255) & ~(size_t)255;
    int* counts = (int*)(ws + off);        off += ((size_t)(N + 1) * 4 + 255) & ~(size_t)255;
    int* allocCtr = counts + N;
    int* row_start = (int*)(ws + off);     off += ((size_t)(N + 1) * 4 + 255) & ~(size_t)255;
    int* cursor = (int*)(ws + off);        off += ((size_t)N * 4 + 255) & ~(size_t)255;
    int* esrc = (int*)(ws + off);          off += ((size_t)(E + 64) * 4 + 255) & ~(size_t)255;
    float* temb = (float*)(ws + off);      off += OUTC * 4;

    const int* srcIdx = ei;
    const int* dstIdx = ei + E;

    hipMemsetAsync(counts, 0, (size_t)(N + 1) * sizeof(int), stream);

    // deterministic host-side occupancy check (same result every call)
    int nb = 0;
    hipError_t qerr = hipOccupancyMaxActiveBlocksPerMultiprocessor(&nb, k_all, TPB, 0);
    int maxg = (qerr == hipSuccess) ? nb * 256 : 0;  // 256 CUs on MI355X
    int G = GMAX;
    if (G > maxg) G = maxg & ~7;

    if (G >= 8) {
        void* args[] = {
            (void*)&x, (void*)&t_emb, (void*)&srcIdx, (void*)&dstIdx,
            (void*)&W, (void*)&b, (void*)&Wt, (void*)&bt, (void*)&out,
            (void*)&xb, (void*)&wtb, (void*)&xwb,
            (void*)&counts, (void*)&row_start, (void*)&cursor, (void*)&allocCtr,
            (void*)&dinv, (void*)&esrc, (void*)&temb,
            (void*)&N, (void*)&E, (void*)&TC, (void*)&Mpad
        };
        hipLaunchCooperativeKernel((void*)k_all, dim3(G), dim3(TPB), args, 0, stream);
    } else {
        k_f0<<<GMAX, TPB, 0, stream>>>(x, t_emb, srcIdx, dstIdx, W, b, Wt, bt, out,
                                       xb, wtb, xwb, counts, row_start, cursor, allocCtr,
                                       dinv, esrc, temb, N, E, TC, Mpad);
        k_f1<<<GMAX, TPB, 0, stream>>>(x, t_emb, srcIdx, dstIdx, W, b, Wt, bt, out,
                                       xb, wtb, xwb, counts, row_start, cursor, allocCtr,
                                       dinv, esrc, temb, N, E, TC, Mpad);
        k_f2<<<GMAX, TPB, 0, stream>>>(x, t_emb, srcIdx, dstIdx, W, b, Wt, bt, out,
                                       xb, wtb, xwb, counts, row_start, cursor, allocCtr,
                                       dinv, esrc, temb, N, E, TC, Mpad);
        k_f3<<<GMAX, TPB, 0, stream>>>(x, t_emb, srcIdx, dstIdx, W, b, Wt, bt, out,
                                       xb, wtb, xwb, counts, row_start, cursor, allocCtr,
                                       dinv, esrc, temb, N, E, TC, Mpad);
    }
}

// Round 12
// 149.461 us; speedup vs baseline: 2.8811x; 2.8811x over previous
//
#include <hip/hip_runtime.h>

#define OUTC 512
#define INC 512
#define NTILE 4
#define TCOL 128   // OUTC / NTILE
#define LDA 72     // 64 + 8 ushort pad: conflict-free ds_read_b128
#define TPB 256

typedef __bf16 bf16x8 __attribute__((ext_vector_type(8)));
typedef float f32x4 __attribute__((ext_vector_type(4)));

static __device__ __forceinline__ unsigned short f2bf(float f) {
    unsigned u = __float_as_uint(f);
    unsigned r = u + 0x7fffu + ((u >> 16) & 1u);  // RNE
    return (unsigned short)(r >> 16);
}
static __device__ __forceinline__ float bflo(unsigned r) { return __uint_as_float(r << 16); }
static __device__ __forceinline__ float bfhi(unsigned r) { return __uint_as_float(r & 0xffff0000u); }
static __device__ __forceinline__ void acc8s(float* a, uint4 v, float n) {
    a[0] += n * bflo(v.x); a[1] += n * bfhi(v.x);
    a[2] += n * bflo(v.y); a[3] += n * bfhi(v.y);
    a[4] += n * bflo(v.z); a[5] += n * bfhi(v.z);
    a[6] += n * bflo(v.w); a[7] += n * bfhi(v.w);
}

// ---------- fused prep: dst-count | X->bf16 | W->bf16^T | temb ----------
__global__ __launch_bounds__(256) void k_prep(const float* __restrict__ x,
                                              const float* __restrict__ W,
                                              const float* __restrict__ t_emb,
                                              const float* __restrict__ Wt,
                                              const float* __restrict__ bt,
                                              const float* __restrict__ b,
                                              const int* __restrict__ dst,
                                              int* __restrict__ counts,
                                              unsigned short* __restrict__ xb,
                                              unsigned short* __restrict__ wtb,
                                              float* __restrict__ temb,
                                              int E, int CB, int XBB,
                                              int M, int Mpad, int TC) {
    __shared__ float smem[32 * 33];
    int bid = blockIdx.x;
    if (bid < CB) {
        int e = bid * 256 + threadIdx.x;
        if (e < E) atomicAdd(&counts[dst[e]], 1);
    } else if (bid < CB + XBB) {
        int idx = (bid - CB) * 256 + threadIdx.x;
        int row = idx >> 6;
        int kg = (idx & 63) * 8;
        ushort4 h0 = make_ushort4(0, 0, 0, 0), h1 = make_ushort4(0, 0, 0, 0);
        if (row < M) {
            float4 v0 = *(const float4*)(x + (size_t)row * INC + kg);
            float4 v1 = *(const float4*)(x + (size_t)row * INC + kg + 4);
            h0 = make_ushort4(f2bf(v0.x), f2bf(v0.y), f2bf(v0.z), f2bf(v0.w));
            h1 = make_ushort4(f2bf(v1.x), f2bf(v1.y), f2bf(v1.z), f2bf(v1.w));
        }
        *(ushort4*)(xb + (size_t)row * INC + kg) = h0;
        *(ushort4*)(xb + (size_t)row * INC + kg + 4) = h1;
    } else if (bid < CB + XBB + 256) {
        int b2 = bid - (CB + XBB);
        int bk = (b2 & 15) * 32, bn = (b2 >> 4) * 32;
        int tx = threadIdx.x & 31, ty = threadIdx.x >> 5;
        for (int r = ty; r < 32; r += 8)
            smem[r * 33 + tx] = W[(size_t)(bk + r) * OUTC + bn + tx];
        __syncthreads();
        for (int r = ty; r < 32; r += 8)
            wtb[(size_t)(bn + r) * INC + bk + tx] = f2bf(smem[tx * 33 + r]);
    } else {
        int j = bid - (CB + XBB + 256);
        int t = threadIdx.x;
        float p = 0.0f;
        for (int k = t; k < TC; k += 256) p += t_emb[k] * Wt[(size_t)k * OUTC + j];
        smem[t] = p;
        __syncthreads();
        for (int s = 128; s > 0; s >>= 1) {
            if (t < s) smem[t] += smem[t + s];
            __syncthreads();
        }
        if (t == 0) temb[j] = smem[0] + bt[j] + b[j];
    }
}

// ---------- fused: MFMA GEMM (blocks [0,GB)) | wave bump-alloc (blocks [GB,GB+40)) ----------
// GEMM: 128x64 tile, BK=64, 4 waves, LDS-staged; xwb col-tiled [tile][Mpad][128], unscaled.
// alloc: wave prefix-scan of counts + 1 atomic/wave -> row_start/cursor/dinv (order-free).
__global__ __launch_bounds__(256) void k_ag(const unsigned short* __restrict__ xb,
                                            const unsigned short* __restrict__ wtb,
                                            unsigned short* __restrict__ xwb,
                                            const int* __restrict__ counts,
                                            int* __restrict__ row_start,
                                            int* __restrict__ cursor,
                                            float* __restrict__ dinv,
                                            int* __restrict__ allocCtr,
                                            int N, int Mpad) {
    __shared__ unsigned short la[128 * LDA];
    __shared__ unsigned short lb[64 * LDA];

    const int bid = blockIdx.x;
    const int tid = threadIdx.x;
    const int GB = (Mpad / 128) * 8;

    if (bid >= GB) {
        // ---- bump-alloc ----
        const int lane = tid & 63;
        const int gwave = ((bid - GB) * TPB + tid) >> 6;  // 0..159
        for (int c0 = gwave * 64; c0 < N; c0 += 160 * 64) {
            int d = c0 + lane;
            int deg = (d < N) ? counts[d] : 0;
            int incl = deg;
#pragma unroll
            for (int off = 1; off < 64; off <<= 1) {
                int v = __shfl_up(incl, off, 64);
                if (lane >= off) incl += v;
            }
            int wtot = __shfl(incl, 63, 64);
            int base = 0;
            if (lane == 63) base = atomicAdd(allocCtr, wtot);
            base = __shfl(base, 63, 64);
            if (d < N) {
                int rs = base + incl - deg;
                row_start[d] = rs;
                cursor[d] = rs;
                dinv[d] = rsqrtf((float)deg + 1.0f);
            }
        }
        return;
    }

    // ---- GEMM ----
    const int n0 = (bid & 7) * 64;
    const int m0 = (bid >> 3) * 128;
    const int lane = tid & 63;
    const int wave = tid >> 6;
    const int wm = wave * 32;
    const int l15 = lane & 15;
    const int k8 = (lane >> 4) * 8;

    f32x4 acc[2][4];
#pragma unroll
    for (int t = 0; t < 2; ++t)
#pragma unroll
        for (int u = 0; u < 4; ++u)
            acc[t][u] = (f32x4){0.f, 0.f, 0.f, 0.f};

    for (int k0 = 0; k0 < INC; k0 += 64) {
#pragma unroll
        for (int i = 0; i < 4; ++i) {
            int f = i * 256 + tid;
            int row = f >> 3, c = f & 7;
            uint4 v = *(const uint4*)(xb + (size_t)(m0 + row) * INC + k0 + c * 8);
            *(uint4*)(&la[row * LDA + c * 8]) = v;
        }
#pragma unroll
        for (int i = 0; i < 2; ++i) {
            int f = i * 256 + tid;
            int row = f >> 3, c = f & 7;
            uint4 v = *(const uint4*)(wtb + (size_t)(n0 + row) * INC + k0 + c * 8);
            *(uint4*)(&lb[row * LDA + c * 8]) = v;
        }
        __syncthreads();

#pragma unroll
        for (int kc = 0; kc < 64; kc += 32) {
            bf16x8 af0 = *(const bf16x8*)(&la[(wm + l15) * LDA + kc + k8]);
            bf16x8 af1 = *(const bf16x8*)(&la[(wm + 16 + l15) * LDA + kc + k8]);
#pragma unroll
            for (int u = 0; u < 4; ++u) {
                bf16x8 bfr = *(const bf16x8*)(&lb[(u * 16 + l15) * LDA + kc + k8]);
                acc[0][u] = __builtin_amdgcn_mfma_f32_16x16x32_bf16(af0, bfr, acc[0][u], 0, 0, 0);
                acc[1][u] = __builtin_amdgcn_mfma_f32_16x16x32_bf16(af1, bfr, acc[1][u], 0, 0, 0);
            }
        }
        __syncthreads();
    }

    const int rbase = (lane >> 4) * 4;
#pragma unroll
    for (int t = 0; t < 2; ++t)
#pragma unroll
        for (int u = 0; u < 4; ++u) {
            int gcol = n0 + u * 16 + l15;
            unsigned short* p = xwb + (size_t)(gcol >> 7) * Mpad * TCOL + (gcol & 127);
#pragma unroll
            for (int r = 0; r < 4; ++r) {
                int grow = m0 + wm + t * 16 + rbase + r;  // < Mpad
                p[(size_t)grow * TCOL] = f2bf(acc[t][u][r]);
            }
        }
}

// ---------- CSR scatter: pack (src, dinv[src]) ----------
__global__ void k_scatter(const int* __restrict__ src, const int* __restrict__ dst,
                          const float* __restrict__ dinv,
                          int* __restrict__ cursor, int2* __restrict__ epk, int E) {
    int e = blockIdx.x * blockDim.x + threadIdx.x;
    if (e < E) {
        int s = src[e];
        int d = dst[e];
        int pos = atomicAdd(&cursor[d], 1);
        epk[pos] = make_int2(s, __float_as_int(dinv[s]));
    }
}

// ---------- XCD-pinned column-tiled gather: 4 edges per row-load instr ----------
__global__ __launch_bounds__(256) void k_gather(const int2* __restrict__ epk,
                                                const int* __restrict__ row_start,
                                                const int* __restrict__ counts,
                                                const unsigned short* __restrict__ xwb,
                                                const float* __restrict__ dinv,
                                                const float* __restrict__ temb,
                                                float* __restrict__ out, int N, int Mpad) {
    const int bid = blockIdx.x;
    const int tile = (bid & 7) >> 1;   // XCD pair {2t,2t+1} -> tile t
    const int node = (bid >> 3) * 8 + (bid & 1) * 4 + (threadIdx.x >> 6);
    if (node >= N) return;
    const int lane = threadIdx.x & 63;
    const int slot = lane >> 4;        // edge slot 0..3
    const int c8 = (lane & 15) * 8;
    const unsigned short* basep = xwb + (size_t)tile * Mpad * TCOL + c8;

    float a[8] = {0.f, 0.f, 0.f, 0.f, 0.f, 0.f, 0.f, 0.f};
    const int s0 = row_start[node];
    const int s1 = s0 + counts[node];
    int i = s0;
    for (; i + 8 <= s1; i += 8) {
        int2 eA = epk[i + slot];
        int2 eB = epk[i + 4 + slot];
        float nA = __int_as_float(eA.y);
        float nB = __int_as_float(eB.y);
        uint4 vA = *(const uint4*)(basep + (size_t)eA.x * TCOL);
        uint4 vB = *(const uint4*)(basep + (size_t)eB.x * TCOL);
        acc8s(a, vA, nA);
        acc8s(a, vB, nB);
    }
    for (; i < s1; i += 4) {
        int idx = i + slot;
        int sA = node;
        float nA = 0.f;
        if (idx < s1) {
            int2 e = epk[idx];
            sA = e.x;
            nA = __int_as_float(e.y);
        }
        uint4 v = *(const uint4*)(basep + (size_t)sA * TCOL);
        acc8s(a, v, nA);
    }
#pragma unroll
    for (int k = 0; k < 8; ++k) {
        a[k] += __shfl_xor(a[k], 16, 64);
        a[k] += __shfl_xor(a[k], 32, 64);
    }
    const float di = dinv[node];
    {
        uint4 v = *(const uint4*)(basep + (size_t)node * TCOL);
        acc8s(a, v, di);  // self-loop term (norm = di*di after final scale)
    }
    if (slot < 2) {
        const int gc = tile * TCOL + c8 + slot * 4;
        float4 tv = *(const float4*)(temb + gc);
        float4 o;
        o.x = di * a[slot * 4 + 0] + tv.x;
        o.y = di * a[slot * 4 + 1] + tv.y;
        o.z = di * a[slot * 4 + 2] + tv.z;
        o.w = di * a[slot * 4 + 3] + tv.w;
        *(float4*)(out + (size_t)node * OUTC + gc) = o;
    }
}

extern "C" void kernel_launch(void* const* d_in, const int* in_sizes, int n_in,
                              void* d_out, int out_size, void* d_ws, size_t ws_size,
                              hipStream_t stream) {
    const float* x     = (const float*)d_in[0];
    const float* t_emb = (const float*)d_in[1];
    const int*   ei    = (const int*)d_in[2];
    const float* W     = (const float*)d_in[3];
    const float* b     = (const float*)d_in[4];
    const float* Wt    = (const float*)d_in[5];
    const float* bt    = (const float*)d_in[6];
    float* out = (float*)d_out;

    const int N  = in_sizes[0] / INC;    // 10000
    const int E  = in_sizes[2] / 2;      // 160000
    const int TC = in_sizes[1];          // 256
    const int Mpad = (N + 127) & ~127;   // 10112

    char* ws = (char*)d_ws;
    size_t off = 0;
    unsigned short* xb  = (unsigned short*)(ws + off); off += (size_t)Mpad * INC * 2;
    unsigned short* xwb = (unsigned short*)(ws + off); off += (size_t)Mpad * OUTC * 2;
    unsigned short* wtb = (unsigned short*)(ws + off); off += (size_t)INC * OUTC * 2;
    float* dinv = (float*)(ws + off);      off += ((size_t)N * 4 + 255) & ~(size_t)255;
    int* counts = (int*)(ws + off);        off += ((size_t)(N + 1) * 4 + 255) & ~(size_t)255;
    int* allocCtr = counts + N;
    int* row_start = (int*)(ws + off);     off += ((size_t)N * 4 + 255) & ~(size_t)255;
    int* cursor = (int*)(ws + off);        off += ((size_t)N * 4 + 255) & ~(size_t)255;
    int2* epk = (int2*)(ws + off);         off += ((size_t)(E + 64) * 8 + 255) & ~(size_t)255;
    float* temb = (float*)(ws + off);      off += OUTC * 4;

    const int* srcIdx = ei;
    const int* dstIdx = ei + E;

    const int CB  = (E + 255) / 256;        // 625
    const int XBB = Mpad * (INC / 8) / 256; // 2528
    const int GB  = (Mpad / 128) * 8;       // 632

    hipMemsetAsync(counts, 0, (size_t)(N + 1) * sizeof(int), stream);
    k_prep<<<CB + XBB + 256 + OUTC, TPB, 0, stream>>>(x, W, t_emb, Wt, bt, b, dstIdx,
                                                      counts, xb, wtb, temb,
                                                      E, CB, XBB, N, Mpad, TC);
    k_ag<<<GB + 40, TPB, 0, stream>>>(xb, wtb, xwb, counts, row_start, cursor,
                                      dinv, allocCtr, N, Mpad);
    k_scatter<<<(E + 255) / 256, TPB, 0, stream>>>(srcIdx, dstIdx, dinv, cursor, epk, E);

    const int gather_blocks = ((N + 7) / 8) * 8;
    k_gather<<<gather_blocks, TPB, 0, stream>>>(epk, row_start, counts, xwb, dinv,
                                                temb, out, N, Mpad);
}